// Round 7
// baseline (276.554 us; speedup 1.0000x reference)
//
#include <hip/hip_runtime.h>
#include <stdint.h>

#define SEQ 4096
#define INDIM 1024
#define NODEDIM 512
#define NH 8
#define HD 64
#define LSTR 72  // padded LDS row stride (ushorts): 144B -> 4-bank rotation per row

typedef __bf16 bf16x8 __attribute__((ext_vector_type(8)));
typedef float f32x4 __attribute__((ext_vector_type(4)));

#define GLOAD_LDS(gp, lp) \
    __builtin_amdgcn_global_load_lds( \
        (const __attribute__((address_space(1))) void*)(gp), \
        (__attribute__((address_space(3))) void*)(lp), 16, 0, 0)

__device__ __forceinline__ unsigned short f2bf(float f) {
    union { float f; uint32_t u; } v; v.f = f;
    uint32_t u = v.u;
    uint32_t r = (u + 0x7fffu + ((u >> 16) & 1u)) >> 16;  // RNE
    return (unsigned short)r;
}

__device__ __forceinline__ float fast_exp2(float x) {
    float r;
    asm volatile("v_exp_f32 %0, %1" : "=v"(r) : "v"(x));
    return r;
}

// load 8 consecutive fp32, convert to bf16x8 (RNE)
__device__ __forceinline__ void cvt8(const float* __restrict__ p, unsigned short* dst) {
    float4 u = *(const float4*)p;
    float4 w = *(const float4*)(p + 4);
    ushort4 a, b;
    a.x = f2bf(u.x); a.y = f2bf(u.y); a.z = f2bf(u.z); a.w = f2bf(u.w);
    b.x = f2bf(w.x); b.y = f2bf(w.y); b.z = f2bf(w.z); b.w = f2bf(w.w);
    *(ushort4*)dst = a;
    *(ushort4*)(dst + 4) = b;
}

// ---------------------------------------------------------------- QKV GEMM (fp32 in, cvt fused)
// Grid (32, 24): x = m-tile (128 rows), y: 0-7 Q head y, 8-15 K head y-8,
// 16-23 V head y-16. Tile 128m x 64n -> 768 blocks = exactly 3/CU (round 6:
// 128x128 grid 384 = 1.5/CU -> half the CUs idle half the time).
// Q/K stored [H,S,D] bf16; V stored transposed [H,D,S] via LDS transpose.
__global__ __launch_bounds__(256) void qkv_gemm(const float* __restrict__ emb,
                                                const float* __restrict__ Wq,
                                                const float* __restrict__ Wk,
                                                const float* __restrict__ Wv,
                                                const float* __restrict__ bq,
                                                const float* __restrict__ bk,
                                                const float* __restrict__ bv,
                                                unsigned short* __restrict__ Qo,
                                                unsigned short* __restrict__ Ko,
                                                unsigned short* __restrict__ VTo) {
    __shared__ unsigned short As[128 * 32];
    __shared__ unsigned short Bs[64 * 32];
    __shared__ unsigned short Ts[64 * 40];  // V-transpose staging (32 s-cols + pad 8)
    const int tid = threadIdx.x;
    const int lane = tid & 63, wave = tid >> 6;
    const int quad = lane >> 4, l16 = lane & 15;
    const int m0 = blockIdx.x * 128;
    const int role = blockIdx.y >> 3;          // 0 Q, 1 K, 2 V
    const int h = blockIdx.y & 7;
    const int n0 = h * 64;                     // row offset within 512-row weight
    const float* __restrict__ Wsrc = (role == 0) ? Wq : (role == 1) ? Wk : Wv;
    const float* __restrict__ bias = (role == 0) ? bq : (role == 1) ? bk : bv;

    f32x4 acc[2][4] = {};

    for (int k0 = 0; k0 < INDIM; k0 += 32) {
        __syncthreads();
        // A: emb fp32 tile 128x32 -> bf16 LDS (512 tasks, 2 passes)
        for (int i = 0; i < 2; ++i) {
            int c = tid + 256 * i;
            int row = c >> 2, seg = c & 3;
            unsigned short tmp[8];
            cvt8(emb + (size_t)(m0 + row) * INDIM + k0 + seg * 8, tmp);
            *(bf16x8*)&As[row * 32 + seg * 8] = *(bf16x8*)tmp;
        }
        // B: weight fp32 tile 64x32 -> bf16 LDS (256 tasks, 1 pass)
        {
            int row = tid >> 2, seg = tid & 3;
            unsigned short tmp[8];
            cvt8(Wsrc + (size_t)(n0 + row) * INDIM + k0 + seg * 8, tmp);
            *(bf16x8*)&Bs[row * 32 + seg * 8] = *(bf16x8*)tmp;
        }
        __syncthreads();
        // wave handles m rows [wave*32, wave*32+32)
        bf16x8 af[2], bf[4];
        for (int mi = 0; mi < 2; ++mi)
            af[mi] = *(const bf16x8*)&As[(wave * 32 + mi * 16 + l16) * 32 + quad * 8];
        for (int ni = 0; ni < 4; ++ni)
            bf[ni] = *(const bf16x8*)&Bs[(ni * 16 + l16) * 32 + quad * 8];
        for (int mi = 0; mi < 2; ++mi)
            for (int ni = 0; ni < 4; ++ni)
                acc[mi][ni] = __builtin_amdgcn_mfma_f32_16x16x32_bf16(af[mi], bf[ni], acc[mi][ni], 0, 0, 0);
    }

    if (role < 2) {
        unsigned short* outp = (role == 0) ? Qo : Ko;
        for (int mi = 0; mi < 2; ++mi)
            for (int ni = 0; ni < 4; ++ni)
                for (int r = 0; r < 4; ++r) {
                    int s = m0 + wave * 32 + mi * 16 + quad * 4 + r;
                    int dd = ni * 16 + l16;
                    float v = acc[mi][ni][r] + bias[n0 + dd];
                    outp[((size_t)h * SEQ + s) * HD + dd] = f2bf(v);
                }
    } else {
        // V: transpose 128(s) x 64(d) through LDS in 4 chunks of 32 s-cols.
        // chunk c's s-rows belong exactly to wave c (wave*32..+32).
        for (int chunk = 0; chunk < 4; ++chunk) {
            __syncthreads();  // Ts reuse across chunks
            if (wave == chunk) {
                for (int mi = 0; mi < 2; ++mi)
                    for (int ni = 0; ni < 4; ++ni) {
                        int ddf = ni * 16 + l16;  // 0..63
                        float bv_ = bias[n0 + ddf];
                        for (int r = 0; r < 4; ++r) {
                            int sl = mi * 16 + quad * 4 + r;  // 0..31
                            Ts[ddf * 40 + sl] = f2bf(acc[mi][ni][r] + bv_);
                        }
                    }
            }
            __syncthreads();
            // copy out: 64 d-rows x 32 s-cols, 16B per lane fully coalesced
            int row = tid >> 2, part = tid & 3;  // 64 x 4
            *(bf16x8*)(VTo + ((size_t)h * HD + row) * SEQ + m0 + chunk * 32 + part * 8) =
                *(const bf16x8*)&Ts[row * 40 + part * 8];
        }
    }
}

// ---------------------------------------------------------------- flash attention (round-4 form: best measured)
// Grid (64, 8, 2). Register-prefetch of next K/V tile; CM loaded at tile top;
// Q folded with Wc*0.125*log2e; max-free softmax; Qs aliased as Ps.
__global__ __launch_bounds__(256, 4) void attn_kernel(const unsigned short* __restrict__ Q,
                                                      const unsigned short* __restrict__ K,
                                                      const unsigned short* __restrict__ VT,
                                                      const float* __restrict__ CM,
                                                      const float* __restrict__ Wc,
                                                      float* __restrict__ O0,
                                                      float* __restrict__ O1,
                                                      float* __restrict__ l0,
                                                      float* __restrict__ l1) {
    __shared__ unsigned short QPs[64 * LSTR];  // Q tile, then reused as P tile
    __shared__ unsigned short Ks[64 * LSTR];
    __shared__ unsigned short Vs[64 * LSTR];   // V^T tile: [d][t]
    const int tid = threadIdx.x;
    const int lane = tid & 63, wave = tid >> 6;
    const int quad = lane >> 4, l16 = lane & 15;
    const int h = blockIdx.y;
    const int q0 = blockIdx.x * 64;
    const int split = blockIdx.z;
    float* __restrict__ Op = split ? O1 : O0;
    float* __restrict__ lp = split ? l1 : l0;
    const float wch = Wc[h] * 0.125f * 1.44269504f;

    const int srow0 = tid >> 3, spart = tid & 7;
    const int srow1 = (tid + 256) >> 3;

    {
        bf16x8 v0 = *(const bf16x8*)(Q + ((size_t)h * SEQ + q0 + srow0) * HD + spart * 8);
        bf16x8 v1 = *(const bf16x8*)(Q + ((size_t)h * SEQ + q0 + srow1) * HD + spart * 8);
        for (int j = 0; j < 8; ++j) {
            v0[j] = (__bf16)((float)v0[j] * wch);
            v1[j] = (__bf16)((float)v1[j] * wch);
        }
        *(bf16x8*)&QPs[srow0 * LSTR + spart * 8] = v0;
        *(bf16x8*)&QPs[srow1 * LSTR + spart * 8] = v1;
    }

    const int tbeg = split * (SEQ / 2);
    const int tend = tbeg + SEQ / 2;

    const unsigned short* kp0 = K + ((size_t)h * SEQ + tbeg + srow0) * HD + spart * 8;
    const unsigned short* kp1 = K + ((size_t)h * SEQ + tbeg + srow1) * HD + spart * 8;
    const unsigned short* vp0 = VT + ((size_t)h * HD + srow0) * SEQ + tbeg + spart * 8;
    const unsigned short* vp1 = VT + ((size_t)h * HD + srow1) * SEQ + tbeg + spart * 8;
    bf16x8 kr0 = *(const bf16x8*)kp0;
    bf16x8 kr1 = *(const bf16x8*)kp1;
    bf16x8 vr0 = *(const bf16x8*)vp0;
    bf16x8 vr1 = *(const bf16x8*)vp1;

    __syncthreads();  // Q staged
    bf16x8 a0 = *(const bf16x8*)&QPs[(wave * 16 + l16) * LSTR + quad * 8];
    bf16x8 a1 = *(const bf16x8*)&QPs[(wave * 16 + l16) * LSTR + 32 + quad * 8];

    f32x4 O[4] = {};
    float l_part[4] = {0.f, 0.f, 0.f, 0.f};
    const float* cmbase = CM + (size_t)(q0 + wave * 16 + quad * 4) * SEQ + l16;

    for (int t0 = tbeg; t0 < tend; t0 += 64) {
        // contact-mask values for THIS tile
        float cmv[4][4];
        for (int r = 0; r < 4; ++r)
            for (int nt = 0; nt < 4; ++nt)
                cmv[r][nt] = cmbase[(size_t)r * SEQ + t0 + nt * 16];

        __syncthreads();
        *(bf16x8*)&Ks[srow0 * LSTR + spart * 8] = kr0;
        *(bf16x8*)&Ks[srow1 * LSTR + spart * 8] = kr1;
        *(bf16x8*)&Vs[srow0 * LSTR + spart * 8] = vr0;
        *(bf16x8*)&Vs[srow1 * LSTR + spart * 8] = vr1;
        __syncthreads();

        if (t0 + 64 < tend) {
            kr0 = *(const bf16x8*)(kp0 + (size_t)(t0 + 64 - tbeg) * HD);
            kr1 = *(const bf16x8*)(kp1 + (size_t)(t0 + 64 - tbeg) * HD);
            vr0 = *(const bf16x8*)(vp0 + (t0 + 64 - tbeg));
            vr1 = *(const bf16x8*)(vp1 + (t0 + 64 - tbeg));
        }

        f32x4 sc[4];
        for (int nt = 0; nt < 4; ++nt) {
            bf16x8 b0 = *(const bf16x8*)&Ks[(nt * 16 + l16) * LSTR + quad * 8];
            bf16x8 b1 = *(const bf16x8*)&Ks[(nt * 16 + l16) * LSTR + 32 + quad * 8];
            f32x4 z = {0.f, 0.f, 0.f, 0.f};
            z = __builtin_amdgcn_mfma_f32_16x16x32_bf16(a0, b0, z, 0, 0, 0);
            z = __builtin_amdgcn_mfma_f32_16x16x32_bf16(a1, b1, z, 0, 0, 0);
            sc[nt] = z;
        }

        for (int r = 0; r < 4; ++r) {
            for (int nt = 0; nt < 4; ++nt) {
                float pv = fast_exp2(sc[nt][r] * cmv[r][nt]);
                l_part[r] += pv;
                union { float f; uint32_t u; } pu; pu.f = pv;
                QPs[(wave * 16 + quad * 4 + r) * LSTR + nt * 16 + l16] =
                    (unsigned short)(pu.u >> 16);
            }
        }

        asm volatile("s_waitcnt lgkmcnt(0)" ::: "memory");

        bf16x8 pa0 = *(const bf16x8*)&QPs[(wave * 16 + l16) * LSTR + quad * 8];
        bf16x8 pa1 = *(const bf16x8*)&QPs[(wave * 16 + l16) * LSTR + 32 + quad * 8];
        for (int nt = 0; nt < 4; ++nt) {
            bf16x8 vb0 = *(const bf16x8*)&Vs[(nt * 16 + l16) * LSTR + quad * 8];
            bf16x8 vb1 = *(const bf16x8*)&Vs[(nt * 16 + l16) * LSTR + 32 + quad * 8];
            f32x4 o = O[nt];
            o = __builtin_amdgcn_mfma_f32_16x16x32_bf16(pa0, vb0, o, 0, 0, 0);
            o = __builtin_amdgcn_mfma_f32_16x16x32_bf16(pa1, vb1, o, 0, 0, 0);
            O[nt] = o;
        }
    }

    for (int r = 0; r < 4; ++r) {
        float s = l_part[r];
        for (int off = 1; off < 16; off <<= 1) s += __shfl_xor(s, off);
        l_part[r] = s;
    }
    if (l16 == 0)
        for (int r = 0; r < 4; ++r)
            lp[(size_t)h * SEQ + q0 + wave * 16 + quad * 4 + r] = l_part[r];
    for (int nt = 0; nt < 4; ++nt)
        for (int r = 0; r < 4; ++r) {
            int sg = q0 + wave * 16 + quad * 4 + r;
            Op[((size_t)h * SEQ + sg) * HD + nt * 16 + l16] = O[nt][r];
        }
}

// ---------------------------------------------------------------- combine splits -> AO bf16
__global__ __launch_bounds__(256) void combine_kernel(const float* __restrict__ O0,
                                                      const float* __restrict__ O1,
                                                      const float* __restrict__ l0,
                                                      const float* __restrict__ l1,
                                                      unsigned short* __restrict__ AO) {
    int idx = blockIdx.x * 256 + threadIdx.x;
    int e = idx * 4;
    int row = e >> 6;  // h*SEQ + s
    float4 a = *(const float4*)(O0 + e);
    float4 b = *(const float4*)(O1 + e);
    float linv = 1.f / (l0[row] + l1[row]);
    ushort4 o;
    o.x = f2bf((a.x + b.x) * linv);
    o.y = f2bf((a.y + b.y) * linv);
    o.z = f2bf((a.z + b.z) * linv);
    o.w = f2bf((a.w + b.w) * linv);
    *(ushort4*)(AO + e) = o;
}

// ---------------------------------------------------------------- output GEMM + residual
// X[4096,512] = AO[4096,512] @ Wo^T[512,512] + bo + emb[:, :512]
// A (bf16) via async global_load_lds; B staged from fp32 Wo (cvt fused).
__global__ __launch_bounds__(256) void out_gemm(const unsigned short* __restrict__ A,
                                                const float* __restrict__ Wo,
                                                const float* __restrict__ bo,
                                                const float* __restrict__ emb,
                                                float* __restrict__ X) {
    __shared__ unsigned short As[64 * 32];
    __shared__ unsigned short Bs[128 * 32];
    const int tid = threadIdx.x;
    const int lane = tid & 63, wave = tid >> 6;
    const int quad = lane >> 4, l16 = lane & 15;
    const int m0 = blockIdx.x * 64;
    const int n0 = blockIdx.y * 128;

    const int srow = tid >> 2, sqq = tid & 3;

    f32x4 acc[8] = {};

    for (int k0 = 0; k0 < NODEDIM; k0 += 32) {
        __syncthreads();
        GLOAD_LDS(A + (size_t)(m0 + srow) * NODEDIM + k0 + sqq * 8, &As[srow * 32 + sqq * 8]);
        for (int i = 0; i < 2; ++i) {
            int c = tid + 256 * i;
            int row = c >> 2, seg = c & 3;
            unsigned short tmp[8];
            cvt8(Wo + (size_t)(n0 + row) * NODEDIM + k0 + seg * 8, tmp);
            *(bf16x8*)&Bs[row * 32 + seg * 8] = *(bf16x8*)tmp;
        }
        __syncthreads();
        bf16x8 af = *(const bf16x8*)&As[(wave * 16 + l16) * 32 + quad * 8];
        for (int ni = 0; ni < 8; ++ni) {
            bf16x8 bf = *(const bf16x8*)&Bs[(ni * 16 + l16) * 32 + quad * 8];
            acc[ni] = __builtin_amdgcn_mfma_f32_16x16x32_bf16(af, bf, acc[ni], 0, 0, 0);
        }
    }

    for (int ni = 0; ni < 8; ++ni)
        for (int r = 0; r < 4; ++r) {
            int s = m0 + wave * 16 + quad * 4 + r;
            int n = n0 + ni * 16 + l16;
            float v = acc[ni][r] + bo[n] + emb[(size_t)s * INDIM + n];
            X[(size_t)s * NODEDIM + n] = v;
        }
}

// ---------------------------------------------------------------- LayerNorm
__global__ __launch_bounds__(256) void ln_kernel(const float* __restrict__ X,
                                                 const float* __restrict__ gamma,
                                                 const float* __restrict__ beta,
                                                 float* __restrict__ out) {
    const int s = blockIdx.x;
    const int n = threadIdx.x * 2;
    float2 v = *(const float2*)&X[(size_t)s * NODEDIM + n];
    float sum = v.x + v.y;
    float sq = v.x * v.x + v.y * v.y;
    for (int off = 32; off > 0; off >>= 1) {
        sum += __shfl_down(sum, off);
        sq += __shfl_down(sq, off);
    }
    __shared__ float ssum[4], ssq[4];
    const int wave = threadIdx.x >> 6, lane = threadIdx.x & 63;
    if (lane == 0) { ssum[wave] = sum; ssq[wave] = sq; }
    __syncthreads();
    float tsum = ssum[0] + ssum[1] + ssum[2] + ssum[3];
    float tsq = ssq[0] + ssq[1] + ssq[2] + ssq[3];
    float mu = tsum * (1.f / 512.f);
    float var = tsq * (1.f / 512.f) - mu * mu;
    float rstd = rsqrtf(var + 1e-5f);
    float2 g = *(const float2*)&gamma[n];
    float2 b = *(const float2*)&beta[n];
    float2 o;
    o.x = (v.x - mu) * rstd * g.x + b.x;
    o.y = (v.y - mu) * rstd * g.y + b.y;
    *(float2*)&out[(size_t)s * NODEDIM + n] = o;
}

// ---------------------------------------------------------------- launch
extern "C" void kernel_launch(void* const* d_in, const int* in_sizes, int n_in,
                              void* d_out, int out_size, void* d_ws, size_t ws_size,
                              hipStream_t stream) {
    const float* emb = (const float*)d_in[0];
    const float* cm  = (const float*)d_in[1];
    const float* Wq  = (const float*)d_in[2];
    const float* bq  = (const float*)d_in[3];
    const float* Wk  = (const float*)d_in[4];
    const float* bk  = (const float*)d_in[5];
    const float* Wv  = (const float*)d_in[6];
    const float* bv  = (const float*)d_in[7];
    const float* Wc  = (const float*)d_in[8];
    const float* Wo  = (const float*)d_in[9];
    const float* bo  = (const float*)d_in[10];
    const float* gamma = (const float*)d_in[11];
    const float* beta  = (const float*)d_in[12];
    float* out = (float*)d_out;

    unsigned short* ws = (unsigned short*)d_ws;
    // layout (ushort units):
    float* O0 = (float*)ws;                             // 8 MB fp32 partial O (split 0)
    float* l0 = (float*)(ws + 4194304);                 // 128 KB
    float* l1 = l0 + NH * SEQ;                          // 128 KB
    unsigned short* Qb  = ws + 4325376;                 // [H,S,D] bf16, 4 MB
    unsigned short* Kb  = Qb + 2097152;                 // [H,S,D] bf16, 4 MB
    unsigned short* VTb = Kb + 2097152;                 // [H,D,S] bf16, 4 MB
    unsigned short* AOb = VTb + 2097152;                // [H,S,D] bf16, 4 MB
    float* X = (float*)(AOb + 2097152);                 // 8 MB fp32
    float* O1 = X;                                      // split-1 partials (X written later)
    // total ws usage ~33.8 MB

    qkv_gemm<<<dim3(32, 24), 256, 0, stream>>>(emb, Wq, Wk, Wv, bq, bk, bv, Qb, Kb, VTb);
    attn_kernel<<<dim3(64, 8, 2), 256, 0, stream>>>(Qb, Kb, VTb, cm, Wc, O0, O1, l0, l1);
    combine_kernel<<<2048, 256, 0, stream>>>(O0, O1, l0, l1, AOb);
    out_gemm<<<dim3(64, 4), 256, 0, stream>>>(AOb, Wo, bo, emb, X);
    ln_kernel<<<4096, 256, 0, stream>>>(X, gamma, beta, out);
}